// Round 8
// baseline (332.124 us; speedup 1.0000x reference)
//
#include <hip/hip_runtime.h>
#include <hip/hip_bf16.h>

#define D_MODEL 1024
#define NHEADS  16
#define HD      64
#define BATCH   4
#define SEQ     2048

#define XELEMS (BATCH * SEQ * D_MODEL)   // 8388608
#define WELEMS (D_MODEL * D_MODEL)       // 1048576

#define KPITCH 72    // Ks/Vt row pitch (shorts): 144 B, bank-balanced
#define PPITCH 72    // Ps row pitch

typedef __attribute__((ext_vector_type(8))) short v8s;   // 8 x bf16 (4 VGPRs)
typedef __attribute__((ext_vector_type(4))) float v4f;   // 4 x f32

using bf16 = __hip_bfloat16;

#define GLD_LDS(gp, lp) \
    __builtin_amdgcn_global_load_lds((const __attribute__((address_space(1))) void*)(gp), \
                                     (__attribute__((address_space(3))) void*)(lp), 16, 0, 0)

#if __has_builtin(__builtin_amdgcn_exp2f)
#define EXP2(x) __builtin_amdgcn_exp2f(x)
#else
#define EXP2(x) exp2f(x)
#endif

// round-to-nearest-even fp32 -> bf16 bits
__device__ __forceinline__ unsigned int f2bf(float f) {
    union { float f; unsigned int u; } c; c.f = f;
    unsigned int u = c.u;
    u += 0x7fffu + ((u >> 16) & 1u);
    return u >> 16;
}

// pack two fp32 -> two bf16 (round-half-up) in one v_perm_b32
__device__ __forceinline__ unsigned int pack_bf16_hu(float lo, float hi) {
    unsigned int a = __float_as_uint(lo) + 0x8000u;
    unsigned int b = __float_as_uint(hi) + 0x8000u;
    return __builtin_amdgcn_perm(b, a, 0x07060302u);
}

// load 8 fp32, pack to 8 bf16 (as uint4)
__device__ __forceinline__ uint4 cvt8(const float* p) {
    float4 f0 = ((const float4*)p)[0];
    float4 f1 = ((const float4*)p)[1];
    uint4 r;
    r.x = f2bf(f0.x) | (f2bf(f0.y) << 16);
    r.y = f2bf(f0.z) | (f2bf(f0.w) << 16);
    r.z = f2bf(f1.x) | (f2bf(f1.y) << 16);
    r.w = f2bf(f1.z) | (f2bf(f1.w) << 16);
    return r;
}

// ---------------------------------------------------------------------------
// Kernel 0: detect bf16 vs fp32 input data (flag=1 -> bf16).
// ---------------------------------------------------------------------------
__global__ void detect_dtype(const unsigned short* __restrict__ x16,
                             int* __restrict__ flag) {
    int lane = threadIdx.x;                      // 64 threads
    unsigned short v = x16[2 * lane];
    int e = (v >> 7) & 0xff;
    bool plaus = (e >= 90) && (e <= 141);
    unsigned long long m = __ballot(plaus);
    if (lane == 0) *flag = (__popcll(m) >= 48) ? 1 : 0;
}

// ---------------------------------------------------------------------------
// Kernel 0.5: convert all inputs to bf16 once (x -> d_out scratch, W/b -> ws).
// ---------------------------------------------------------------------------
__global__ __launch_bounds__(256) void convert_inputs(
    const void* __restrict__ x,
    const void* __restrict__ wq, const void* __restrict__ wk,
    const void* __restrict__ wv,
    const void* __restrict__ bq, const void* __restrict__ bk,
    const void* __restrict__ bv,
    bf16* __restrict__ xbf, bf16* __restrict__ wbf, bf16* __restrict__ bbf,
    const int* __restrict__ flag)
{
    const int isbf = *flag;
    long g = (long)blockIdx.x * 256 + threadIdx.x;   // one group = 8 elements
    const long xg = XELEMS / 8;          // 1048576
    const long wg = WELEMS / 8;          // 131072
    const long bg = D_MODEL / 8;         // 128
    const void* src; bf16* dst; long off;
    if      (g < xg)                  { src = x;  dst = xbf;              off = g; }
    else if (g < xg + wg)             { src = wq; dst = wbf;              off = g - xg; }
    else if (g < xg + 2*wg)           { src = wk; dst = wbf + WELEMS;     off = g - xg - wg; }
    else if (g < xg + 3*wg)           { src = wv; dst = wbf + 2*WELEMS;   off = g - xg - 2*wg; }
    else if (g < xg + 3*wg + bg)      { src = bq; dst = bbf;              off = g - xg - 3*wg; }
    else if (g < xg + 3*wg + 2*bg)    { src = bk; dst = bbf + D_MODEL;    off = g - xg - 3*wg - bg; }
    else if (g < xg + 3*wg + 3*bg)    { src = bv; dst = bbf + 2*D_MODEL;  off = g - xg - 3*wg - 2*bg; }
    else return;
    uint4 r = isbf ? ((const uint4*)src)[off]
                   : cvt8((const float*)src + off * 8);
    ((uint4*)dst)[off] = r;
}

// ---------------------------------------------------------------------------
// Kernel 1: fused QKV projection (all-bf16, async global_load_lds staging).
// y = x @ W.T + b. Q,K -> [B,H,S,64]; V -> TRANSPOSED [B,H,64,S].
// Q gets log2(e)/32 folded in (softmax then uses exp2 directly).
// ---------------------------------------------------------------------------
__global__ __launch_bounds__(256) void qkv_gemm(
    const bf16* __restrict__ xbf, const bf16* __restrict__ wbf,
    const bf16* __restrict__ bbf,
    bf16* __restrict__ qout, bf16* __restrict__ kout, bf16* __restrict__ vout)
{
    __shared__ bf16 Atile[128 * 32];
    __shared__ bf16 Btile[128 * 32];

    const int z = blockIdx.z;
    const bf16* W    = wbf + (size_t)z * WELEMS;
    const bf16* bias = bbf + z * D_MODEL;
    bf16* out = (z == 0) ? qout : (z == 1) ? kout : vout;
    const float scale = (z == 0) ? (1.4426950408889634f / 32.0f) : 1.0f;

    const int tid  = threadIdx.x;
    const int lane = tid & 63;
    const int wave = tid >> 6;
    const int m0w  = (wave >> 1) * 64;
    const int n0w  = (wave & 1) * 64;
    const int m_base = blockIdx.x * 128;
    const int n_base = blockIdx.y * 128;

    const int lm   = lane & 15;
    const int quad = lane >> 4;
    const int lk   = quad * 8;

    v4f acc[4][4] = {};

    for (int k0 = 0; k0 < D_MODEL; k0 += 32) {
        __syncthreads();   // previous iteration's LDS reads complete
        #pragma unroll
        for (int p = 0; p < 2; ++p) {
            int chunk = wave + 4 * p;                    // 16 rows (1 KB) per chunk
            int row   = chunk * 16 + (lane >> 2);
            const bf16* ga = xbf + (size_t)(m_base + row) * D_MODEL + k0 + (lane & 3) * 8;
            const bf16* gb = W   + (size_t)(n_base + row) * D_MODEL + k0 + (lane & 3) * 8;
            GLD_LDS(ga, Atile + chunk * 16 * 32);
            GLD_LDS(gb, Btile + chunk * 16 * 32);
        }
        __syncthreads();   // drains vmcnt (global_load_lds) for all waves

        v8s afrag[4], bfrag[4];
        #pragma unroll
        for (int mt = 0; mt < 4; ++mt)
            afrag[mt] = *(const v8s*)(Atile + (m0w + mt * 16 + lm) * 32 + lk);
        #pragma unroll
        for (int nt = 0; nt < 4; ++nt)
            bfrag[nt] = *(const v8s*)(Btile + (n0w + nt * 16 + lm) * 32 + lk);
        #pragma unroll
        for (int mt = 0; mt < 4; ++mt)
            #pragma unroll
            for (int nt = 0; nt < 4; ++nt)
                acc[mt][nt] = __builtin_amdgcn_mfma_f32_16x16x32_bf16(
                    afrag[mt], bfrag[nt], acc[mt][nt], 0, 0, 0);
    }

    // epilogue: +bias, *scale; Q/K -> [B,H,S,64], V -> [B,H,64,S] (packed)
    #pragma unroll
    for (int nt = 0; nt < 4; ++nt) {
        int n = n_base + n0w + nt * 16 + lm;
        float bb = __bfloat162float(bias[n]);
        int h = n >> 6, d = n & 63;
        #pragma unroll
        for (int mt = 0; mt < 4; ++mt) {
            if (z == 2) {
                int m = m_base + m0w + mt * 16 + quad * 4;
                int b = m >> 11, s = m & (SEQ - 1);
                float p0 = acc[mt][nt][0] + bb;
                float p1 = acc[mt][nt][1] + bb;
                float p2 = acc[mt][nt][2] + bb;
                float p3 = acc[mt][nt][3] + bb;
                uint2 pk;
                pk.x = pack_bf16_hu(p0, p1);
                pk.y = pack_bf16_hu(p2, p3);
                size_t bh = (size_t)(b * NHEADS + h);
                *(uint2*)(out + (((bh << 6) + d) << 11) + s) = pk;
            } else {
                #pragma unroll
                for (int r = 0; r < 4; ++r) {
                    int m = m_base + m0w + mt * 16 + quad * 4 + r;
                    int b = m >> 11, s = m & (SEQ - 1);
                    float vv = (acc[mt][nt][r] + bb) * scale;
                    size_t bh = (size_t)(b * NHEADS + h);
                    out[(((bh << 11) + s) << 6) + d] = __float2bfloat16(vv);
                }
            }
        }
    }
}

// ---------------------------------------------------------------------------
// Kernel 2: flash attention. R7 structure (cooperative LDS staging, exp2
// softmax without running max, wave-private Ps roundtrip) plus:
//  - XCD-aware 1D grid swizzle: all 16 q-tiles of a head map to one XCD
//    (l&7) so K/V stay resident in that XCD's 4MB L2 (was 3x L2-miss ampl.)
//  - 2-deep register prefetch (phase ping-pong): staging regs for tile t+2
//    issued at tile t -> ~2 compute sections of latency cover.
// ---------------------------------------------------------------------------
__global__ __launch_bounds__(256) void attn(
    const bf16* __restrict__ q, const bf16* __restrict__ k,
    const bf16* __restrict__ vT, void* __restrict__ out,
    const int* __restrict__ flag)
{
    __shared__ bf16 Ks[64 * KPITCH];    // [s_k][d]    9216 B
    __shared__ bf16 Vt[64 * KPITCH];    // [d][s_k]    9216 B
    __shared__ bf16 Ps[128 * PPITCH];   // [q][s_k]   18432 B (wave-private rows)

    const int isbf = *flag;

    // XCD-aware decode: l&7 = XCD slot; all q-tiles of a head share it
    const int l   = blockIdx.x;          // 0..1023
    const int idx = l >> 3;              // 0..127
    const int q0  = (idx & 15) * 128;
    const int bh  = (l & 7) + ((idx >> 4) << 3);   // 0..63
    const int b   = bh >> 4, h = bh & 15;
    const size_t head_base  = (size_t)bh * SEQ * HD;   // q,k: [B,H,S,64]
    const size_t head_baseT = (size_t)bh * HD * SEQ;   // vT:  [B,H,64,S]

    const int tid  = threadIdx.x;
    const int lane = tid & 63;
    const int wave = tid >> 6;
    const int lm   = lane & 15;
    const int quad = lane >> 4;

    // Q fragments in registers (serve as B operand of K.Q^T)
    v8s aq[2][2];
    #pragma unroll
    for (int mt = 0; mt < 2; ++mt)
        #pragma unroll
        for (int kb = 0; kb < 2; ++kb)
            aq[mt][kb] = *(const v8s*)(q + head_base
                          + (size_t)(q0 + wave * 32 + mt * 16 + lm) * HD
                          + kb * 32 + quad * 8);

    float l_acc[2] = { 0.0f, 0.0f };
    v4f   O[2][4] = {};

    const int srow = tid >> 3;            // 0..31 (+32 for p=1)
    const int scol = (tid & 7) * 8;       // 0..56

    // 2-deep prefetch: phase arrays, tiles 0 and 1 in flight before the loop
    uint4 kreg[2][2], vreg[2][2];
    #pragma unroll
    for (int ph = 0; ph < 2; ++ph)
        #pragma unroll
        for (int p = 0; p < 2; ++p) {
            int row = srow + 32 * p;
            kreg[ph][p] = *(const uint4*)(k  + head_base
                            + (size_t)(ph * 64 + row) * HD + scol);
            vreg[ph][p] = *(const uint4*)(vT + head_baseT
                            + (size_t)row * SEQ + ph * 64 + scol);
        }

    #pragma unroll 2
    for (int t = 0; t < 32; ++t) {
        const int ph  = t & 1;
        const int kv0 = t * 64;
        __syncthreads();   // all waves done reading previous Ks/Vt
        #pragma unroll
        for (int p = 0; p < 2; ++p) {
            int row = srow + 32 * p;
            *(uint4*)(Ks + row * KPITCH + scol) = kreg[ph][p];
            *(uint4*)(Vt + row * KPITCH + scol) = vreg[ph][p];
        }
        __syncthreads();

        // issue tile t+2's loads; ~2 compute sections of cover
        if (t + 2 < 32) {
            #pragma unroll
            for (int p = 0; p < 2; ++p) {
                int row = srow + 32 * p;
                kreg[ph][p] = *(const uint4*)(k  + head_base
                                + (size_t)(kv0 + 128 + row) * HD + scol);
                vreg[ph][p] = *(const uint4*)(vT + head_baseT
                                + (size_t)row * SEQ + kv0 + 128 + scol);
            }
        }

        // S^T = K . Q^T : rows s_k (4 subtiles), cols s_q (2 subtiles/wave)
        v4f sc[4][2] = {};
        #pragma unroll
        for (int kb = 0; kb < 2; ++kb) {
            v8s kf[4];
            #pragma unroll
            for (int kt = 0; kt < 4; ++kt)
                kf[kt] = *(const v8s*)(Ks + (kt * 16 + lm) * KPITCH + kb * 32 + quad * 8);
            #pragma unroll
            for (int kt = 0; kt < 4; ++kt)
                #pragma unroll
                for (int mt = 0; mt < 2; ++mt)
                    sc[kt][mt] = __builtin_amdgcn_mfma_f32_16x16x32_bf16(
                        kf[kt], aq[mt][kb], sc[kt][mt], 0, 0, 0);
        }

        // exp2 (scores already in log2 domain), accumulate l, pack P -> Ps
        #pragma unroll
        for (int mt = 0; mt < 2; ++mt) {
            #pragma unroll
            for (int kt = 0; kt < 4; ++kt) {
                float p0 = EXP2(sc[kt][mt][0]);
                float p1 = EXP2(sc[kt][mt][1]);
                float p2 = EXP2(sc[kt][mt][2]);
                float p3 = EXP2(sc[kt][mt][3]);
                l_acc[mt] += (p0 + p1) + (p2 + p3);
                uint2 pk;
                pk.x = pack_bf16_hu(p0, p1);
                pk.y = pack_bf16_hu(p2, p3);
                *(uint2*)(Ps + (wave * 32 + mt * 16 + lm) * PPITCH
                             + kt * 16 + quad * 4) = pk;
            }
        }
        // Ps rows are wave-private: lgkmcnt ordering suffices, no barrier

        // O += P . V
        #pragma unroll
        for (int kk = 0; kk < 2; ++kk) {
            v8s ap[2], bv8[4];
            #pragma unroll
            for (int mt = 0; mt < 2; ++mt)
                ap[mt] = *(const v8s*)(Ps + (wave * 32 + mt * 16 + lm) * PPITCH
                                          + kk * 32 + quad * 8);
            #pragma unroll
            for (int dt = 0; dt < 4; ++dt)
                bv8[dt] = *(const v8s*)(Vt + (dt * 16 + lm) * KPITCH
                                           + kk * 32 + quad * 8);
            #pragma unroll
            for (int mt = 0; mt < 2; ++mt)
                #pragma unroll
                for (int dt = 0; dt < 4; ++dt)
                    O[mt][dt] = __builtin_amdgcn_mfma_f32_16x16x32_bf16(
                        ap[mt], bv8[dt], O[mt][dt], 0, 0, 0);
        }
    }

    // final l reduction: quads hold disjoint s_k partials for same column lm
    float inv[2];
    #pragma unroll
    for (int mt = 0; mt < 2; ++mt) {
        float lsum = l_acc[mt];
        lsum += __shfl_xor(lsum, 16, 64);
        lsum += __shfl_xor(lsum, 32, 64);
        inv[mt] = 1.0f / lsum;
    }

    // epilogue: O row q needs inv from column-lane q: broadcast via shfl
    #pragma unroll
    for (int mt = 0; mt < 2; ++mt) {
        #pragma unroll
        for (int r = 0; r < 4; ++r) {
            float ir = __shfl(inv[mt], quad * 4 + r, 64);
            int s = q0 + wave * 32 + mt * 16 + quad * 4 + r;
            #pragma unroll
            for (int dt = 0; dt < 4; ++dt) {
                int d = dt * 16 + lm;
                size_t off = (size_t)(b * SEQ + s) * D_MODEL + h * HD + d;
                float val = O[mt][dt][r] * ir;
                if (isbf) ((bf16*)out)[off] = __float2bfloat16(val);
                else      ((float*)out)[off] = val;
            }
        }
    }
}

extern "C" void kernel_launch(void* const* d_in, const int* in_sizes, int n_in,
                              void* d_out, int out_size, void* d_ws, size_t ws_size,
                              hipStream_t stream) {
    const void* x  = d_in[0];
    const void* Wq = d_in[1];
    const void* bq = d_in[2];
    const void* Wk = d_in[3];
    const void* bk = d_in[4];
    const void* Wv = d_in[5];
    const void* bv = d_in[6];

    char* ws = (char*)d_ws;
    int*  flag = (int*)ws;
    bf16* wbf  = (bf16*)(ws + 256);                              // 3 * 1048576 bf16
    bf16* bbf  = (bf16*)(ws + 256 + 3 * (size_t)WELEMS * 2);     // 3 * 1024 bf16
    bf16* qws  = (bf16*)(ws + 256 + 3 * (size_t)WELEMS * 2 + 8192);
    const size_t per = (size_t)BATCH * NHEADS * SEQ * HD;        // 8,388,608
    bf16* kws = qws + per;
    bf16* vws = kws + per;                                       // [B,H,64,S]

    // x (bf16) scratch lives in d_out: dead until attn's final write.
    bf16* xbf = (bf16*)d_out;

    detect_dtype<<<1, 64, 0, stream>>>((const unsigned short*)x, flag);

    const long ngroups = (long)XELEMS / 8 + 3L * (WELEMS / 8) + 3L * (D_MODEL / 8);
    convert_inputs<<<(int)((ngroups + 255) / 256), 256, 0, stream>>>(
        x, Wq, Wk, Wv, bq, bk, bv, xbf, wbf, bbf, flag);

    dim3 g1(64, 8, 3);        // M/128, N/128, {q,k,v}
    qkv_gemm<<<g1, 256, 0, stream>>>(xbf, wbf, bbf, qws, kws, vws);

    attn<<<1024, 256, 0, stream>>>(qws, kws, vws, d_out, flag);
}

// Round 9
// 251.496 us; speedup vs baseline: 1.3206x; 1.3206x over previous
//
#include <hip/hip_runtime.h>
#include <hip/hip_bf16.h>

#define D_MODEL 1024
#define NHEADS  16
#define HD      64
#define BATCH   4
#define SEQ     2048

#define XELEMS (BATCH * SEQ * D_MODEL)   // 8388608
#define WELEMS (D_MODEL * D_MODEL)       // 1048576

#define PPITCH 72    // Ps row pitch (shorts): 144 B, bank-balanced

typedef __attribute__((ext_vector_type(8))) short v8s;   // 8 x bf16 (4 VGPRs)
typedef __attribute__((ext_vector_type(4))) float v4f;   // 4 x f32

using bf16 = __hip_bfloat16;

#define GLD_LDS(gp, lp) \
    __builtin_amdgcn_global_load_lds((const __attribute__((address_space(1))) void*)(gp), \
                                     (__attribute__((address_space(3))) void*)(lp), 16, 0, 0)

#if __has_builtin(__builtin_amdgcn_exp2f)
#define EXP2(x) __builtin_amdgcn_exp2f(x)
#else
#define EXP2(x) exp2f(x)
#endif

// round-to-nearest-even fp32 -> bf16 bits
__device__ __forceinline__ unsigned int f2bf(float f) {
    union { float f; unsigned int u; } c; c.f = f;
    unsigned int u = c.u;
    u += 0x7fffu + ((u >> 16) & 1u);
    return u >> 16;
}

// pack two fp32 -> two bf16 (round-half-up) in one v_perm_b32
__device__ __forceinline__ unsigned int pack_bf16_hu(float lo, float hi) {
    unsigned int a = __float_as_uint(lo) + 0x8000u;
    unsigned int b = __float_as_uint(hi) + 0x8000u;
    return __builtin_amdgcn_perm(b, a, 0x07060302u);
}

// load 8 fp32, pack to 8 bf16 (as uint4)
__device__ __forceinline__ uint4 cvt8(const float* p) {
    float4 f0 = ((const float4*)p)[0];
    float4 f1 = ((const float4*)p)[1];
    uint4 r;
    r.x = f2bf(f0.x) | (f2bf(f0.y) << 16);
    r.y = f2bf(f0.z) | (f2bf(f0.w) << 16);
    r.z = f2bf(f1.x) | (f2bf(f1.y) << 16);
    r.w = f2bf(f1.z) | (f2bf(f1.w) << 16);
    return r;
}

// ---------------------------------------------------------------------------
// Kernel 0: detect bf16 vs fp32 input data (flag=1 -> bf16).
// ---------------------------------------------------------------------------
__global__ void detect_dtype(const unsigned short* __restrict__ x16,
                             int* __restrict__ flag) {
    int lane = threadIdx.x;                      // 64 threads
    unsigned short v = x16[2 * lane];
    int e = (v >> 7) & 0xff;
    bool plaus = (e >= 90) && (e <= 141);
    unsigned long long m = __ballot(plaus);
    if (lane == 0) *flag = (__popcll(m) >= 48) ? 1 : 0;
}

// ---------------------------------------------------------------------------
// Kernel 0.5: convert all inputs to bf16 once (x -> d_out scratch, W/b -> ws).
// ---------------------------------------------------------------------------
__global__ __launch_bounds__(256) void convert_inputs(
    const void* __restrict__ x,
    const void* __restrict__ wq, const void* __restrict__ wk,
    const void* __restrict__ wv,
    const void* __restrict__ bq, const void* __restrict__ bk,
    const void* __restrict__ bv,
    bf16* __restrict__ xbf, bf16* __restrict__ wbf, bf16* __restrict__ bbf,
    const int* __restrict__ flag)
{
    const int isbf = *flag;
    long g = (long)blockIdx.x * 256 + threadIdx.x;   // one group = 8 elements
    const long xg = XELEMS / 8;          // 1048576
    const long wg = WELEMS / 8;          // 131072
    const long bg = D_MODEL / 8;         // 128
    const void* src; bf16* dst; long off;
    if      (g < xg)                  { src = x;  dst = xbf;              off = g; }
    else if (g < xg + wg)             { src = wq; dst = wbf;              off = g - xg; }
    else if (g < xg + 2*wg)           { src = wk; dst = wbf + WELEMS;     off = g - xg - wg; }
    else if (g < xg + 3*wg)           { src = wv; dst = wbf + 2*WELEMS;   off = g - xg - 2*wg; }
    else if (g < xg + 3*wg + bg)      { src = bq; dst = bbf;              off = g - xg - 3*wg; }
    else if (g < xg + 3*wg + 2*bg)    { src = bk; dst = bbf + D_MODEL;    off = g - xg - 3*wg - bg; }
    else if (g < xg + 3*wg + 3*bg)    { src = bv; dst = bbf + 2*D_MODEL;  off = g - xg - 3*wg - 2*bg; }
    else return;
    uint4 r = isbf ? ((const uint4*)src)[off]
                   : cvt8((const float*)src + off * 8);
    ((uint4*)dst)[off] = r;
}

// ---------------------------------------------------------------------------
// Kernel 1: fused QKV projection (all-bf16, async global_load_lds staging).
// y = x @ W.T + b. Q,K -> [B,H,S,64]; V -> TRANSPOSED [B,H,64,S].
// Q gets log2(e)/32 folded in (softmax then uses exp2 directly).
// ---------------------------------------------------------------------------
__global__ __launch_bounds__(256, 2) void qkv_gemm(
    const bf16* __restrict__ xbf, const bf16* __restrict__ wbf,
    const bf16* __restrict__ bbf,
    bf16* __restrict__ qout, bf16* __restrict__ kout, bf16* __restrict__ vout)
{
    __shared__ bf16 Atile[128 * 32];
    __shared__ bf16 Btile[128 * 32];

    const int z = blockIdx.z;
    const bf16* W    = wbf + (size_t)z * WELEMS;
    const bf16* bias = bbf + z * D_MODEL;
    bf16* out = (z == 0) ? qout : (z == 1) ? kout : vout;
    const float scale = (z == 0) ? (1.4426950408889634f / 32.0f) : 1.0f;

    const int tid  = threadIdx.x;
    const int lane = tid & 63;
    const int wave = tid >> 6;
    const int m0w  = (wave >> 1) * 64;
    const int n0w  = (wave & 1) * 64;
    const int m_base = blockIdx.x * 128;
    const int n_base = blockIdx.y * 128;

    const int lm   = lane & 15;
    const int quad = lane >> 4;
    const int lk   = quad * 8;

    v4f acc[4][4] = {};

    for (int k0 = 0; k0 < D_MODEL; k0 += 32) {
        __syncthreads();   // previous iteration's LDS reads complete
        #pragma unroll
        for (int p = 0; p < 2; ++p) {
            int chunk = wave + 4 * p;                    // 16 rows (1 KB) per chunk
            int row   = chunk * 16 + (lane >> 2);
            const bf16* ga = xbf + (size_t)(m_base + row) * D_MODEL + k0 + (lane & 3) * 8;
            const bf16* gb = W   + (size_t)(n_base + row) * D_MODEL + k0 + (lane & 3) * 8;
            GLD_LDS(ga, Atile + chunk * 16 * 32);
            GLD_LDS(gb, Btile + chunk * 16 * 32);
        }
        __syncthreads();   // drains vmcnt (global_load_lds) for all waves

        v8s afrag[4], bfrag[4];
        #pragma unroll
        for (int mt = 0; mt < 4; ++mt)
            afrag[mt] = *(const v8s*)(Atile + (m0w + mt * 16 + lm) * 32 + lk);
        #pragma unroll
        for (int nt = 0; nt < 4; ++nt)
            bfrag[nt] = *(const v8s*)(Btile + (n0w + nt * 16 + lm) * 32 + lk);
        #pragma unroll
        for (int mt = 0; mt < 4; ++mt)
            #pragma unroll
            for (int nt = 0; nt < 4; ++nt)
                acc[mt][nt] = __builtin_amdgcn_mfma_f32_16x16x32_bf16(
                    afrag[mt], bfrag[nt], acc[mt][nt], 0, 0, 0);
    }

    // epilogue: +bias, *scale; Q/K -> [B,H,S,64], V -> [B,H,64,S] (packed)
    #pragma unroll
    for (int nt = 0; nt < 4; ++nt) {
        int n = n_base + n0w + nt * 16 + lm;
        float bb = __bfloat162float(bias[n]);
        int h = n >> 6, d = n & 63;
        #pragma unroll
        for (int mt = 0; mt < 4; ++mt) {
            if (z == 2) {
                int m = m_base + m0w + mt * 16 + quad * 4;
                int b = m >> 11, s = m & (SEQ - 1);
                float p0 = acc[mt][nt][0] + bb;
                float p1 = acc[mt][nt][1] + bb;
                float p2 = acc[mt][nt][2] + bb;
                float p3 = acc[mt][nt][3] + bb;
                uint2 pk;
                pk.x = pack_bf16_hu(p0, p1);
                pk.y = pack_bf16_hu(p2, p3);
                size_t bh = (size_t)(b * NHEADS + h);
                *(uint2*)(out + (((bh << 6) + d) << 11) + s) = pk;
            } else {
                #pragma unroll
                for (int r = 0; r < 4; ++r) {
                    int m = m_base + m0w + mt * 16 + quad * 4 + r;
                    int b = m >> 11, s = m & (SEQ - 1);
                    float vv = (acc[mt][nt][r] + bb) * scale;
                    size_t bh = (size_t)(b * NHEADS + h);
                    out[(((bh << 11) + s) << 6) + d] = __float2bfloat16(vv);
                }
            }
        }
    }
}

// ---------------------------------------------------------------------------
// Kernel 2: flash attention. Staging registers ELIMINATED (R4-R8 evidence:
// register arrays live across barriers get spilled to scratch -> 200-440 MB
// of HBM write traffic). K/V staged via async global_load_lds into
// FRAGMENT-MAJOR LDS layout (DMA needs wave-uniform dest + lane*16B, so no
// padded pitch; chunk index = subtile, lane slot = lm*4+quad -> reader
// ds_read_b128 pattern identical to the m97 GEMM's, known conflict-clean).
// Keeps: XCD swizzle (FETCH 147->47 MB), exp2 softmax w/o running max,
// wave-private Ps roundtrip, V^T pre-transposed input.
// LDS 34.8 KB -> 4 blocks/CU; launch_bounds(256,4) -> 128 VGPR, no spill.
// ---------------------------------------------------------------------------
__global__ __launch_bounds__(256, 4) void attn(
    const bf16* __restrict__ q, const bf16* __restrict__ k,
    const bf16* __restrict__ vT, void* __restrict__ out,
    const int* __restrict__ flag)
{
    __shared__ bf16 Ks[8 * 512];        // fragment-major: [kt*2+kb][lane*8] 8192 B
    __shared__ bf16 Vt[8 * 512];        // fragment-major: [kk*4+dt][lane*8] 8192 B
    __shared__ bf16 Ps[128 * PPITCH];   // [q][s_k] 18432 B (wave-private rows)

    const int isbf = *flag;

    // XCD-aware decode: l&7 = XCD slot; all q-tiles of a head share it
    const int l   = blockIdx.x;          // 0..1023
    const int idx = l >> 3;              // 0..127
    const int q0  = (idx & 15) * 128;
    const int bh  = (l & 7) + ((idx >> 4) << 3);   // 0..63
    const int b   = bh >> 4, h = bh & 15;
    const size_t head_base  = (size_t)bh * SEQ * HD;   // q,k: [B,H,S,64]
    const size_t head_baseT = (size_t)bh * HD * SEQ;   // vT:  [B,H,64,S]

    const int tid  = threadIdx.x;
    const int lane = tid & 63;
    const int wave = tid >> 6;
    const int lm   = lane & 15;
    const int quad = lane >> 4;

    // staging decode (DMA lane -> source element)
    const int slm = lane >> 2;           // 0..15: row within 16-row subtile
    const int sq  = lane & 3;            // 0..3 : 16-B column slot
    // reader offset within a fragment chunk (shorts)
    const int fidx = (lm * 4 + quad) * 8;

    // Q fragments in registers (serve as B operand of K.Q^T)
    v8s aq[2][2];
    #pragma unroll
    for (int mt = 0; mt < 2; ++mt)
        #pragma unroll
        for (int kb = 0; kb < 2; ++kb)
            aq[mt][kb] = *(const v8s*)(q + head_base
                          + (size_t)(q0 + wave * 32 + mt * 16 + lm) * HD
                          + kb * 32 + quad * 8);

    float l_acc[2] = { 0.0f, 0.0f };
    v4f   O[2][4] = {};

    for (int kv0 = 0; kv0 < SEQ; kv0 += 64) {
        __syncthreads();   // all waves done reading previous Ks/Vt
        // stage K tile: 8 chunks of 1 KB, 2 per wave; chunk c = kt*2+kb
        #pragma unroll
        for (int j = 0; j < 2; ++j) {
            int c  = wave * 2 + j;
            int kt = c >> 1, kb = c & 1;
            const bf16* ga = k + head_base
                + (size_t)(kv0 + kt * 16 + slm) * HD + kb * 32 + sq * 8;
            GLD_LDS(ga, Ks + c * 512);
        }
        // stage V tile: chunk c = kk*4+dt
        #pragma unroll
        for (int j = 0; j < 2; ++j) {
            int c  = wave * 2 + j;
            int kk = c >> 2, dt = c & 3;
            const bf16* gv = vT + head_baseT
                + (size_t)(dt * 16 + slm) * SEQ + kv0 + kk * 32 + sq * 8;
            GLD_LDS(gv, Vt + c * 512);
        }
        __syncthreads();   // vmcnt drain + barrier: tiles visible to all

        // S^T = K . Q^T : rows s_k (4 subtiles), cols s_q (2 subtiles/wave)
        v4f sc[4][2] = {};
        #pragma unroll
        for (int kb = 0; kb < 2; ++kb) {
            v8s kf[4];
            #pragma unroll
            for (int kt = 0; kt < 4; ++kt)
                kf[kt] = *(const v8s*)(Ks + (kt * 2 + kb) * 512 + fidx);
            #pragma unroll
            for (int kt = 0; kt < 4; ++kt)
                #pragma unroll
                for (int mt = 0; mt < 2; ++mt)
                    sc[kt][mt] = __builtin_amdgcn_mfma_f32_16x16x32_bf16(
                        kf[kt], aq[mt][kb], sc[kt][mt], 0, 0, 0);
        }

        // exp2 (scores already in log2 domain), accumulate l, pack P -> Ps
        #pragma unroll
        for (int mt = 0; mt < 2; ++mt) {
            #pragma unroll
            for (int kt = 0; kt < 4; ++kt) {
                float p0 = EXP2(sc[kt][mt][0]);
                float p1 = EXP2(sc[kt][mt][1]);
                float p2 = EXP2(sc[kt][mt][2]);
                float p3 = EXP2(sc[kt][mt][3]);
                l_acc[mt] += (p0 + p1) + (p2 + p3);
                uint2 pk;
                pk.x = pack_bf16_hu(p0, p1);
                pk.y = pack_bf16_hu(p2, p3);
                *(uint2*)(Ps + (wave * 32 + mt * 16 + lm) * PPITCH
                             + kt * 16 + quad * 4) = pk;
            }
        }
        // Ps rows are wave-private: lgkmcnt ordering suffices, no barrier

        // O += P . V
        #pragma unroll
        for (int kk = 0; kk < 2; ++kk) {
            v8s ap[2], bv8[4];
            #pragma unroll
            for (int mt = 0; mt < 2; ++mt)
                ap[mt] = *(const v8s*)(Ps + (wave * 32 + mt * 16 + lm) * PPITCH
                                          + kk * 32 + quad * 8);
            #pragma unroll
            for (int dt = 0; dt < 4; ++dt)
                bv8[dt] = *(const v8s*)(Vt + (kk * 4 + dt) * 512 + fidx);
            #pragma unroll
            for (int mt = 0; mt < 2; ++mt)
                #pragma unroll
                for (int dt = 0; dt < 4; ++dt)
                    O[mt][dt] = __builtin_amdgcn_mfma_f32_16x16x32_bf16(
                        ap[mt], bv8[dt], O[mt][dt], 0, 0, 0);
        }
    }

    // final l reduction: quads hold disjoint s_k partials for same column lm
    float inv[2];
    #pragma unroll
    for (int mt = 0; mt < 2; ++mt) {
        float lsum = l_acc[mt];
        lsum += __shfl_xor(lsum, 16, 64);
        lsum += __shfl_xor(lsum, 32, 64);
        inv[mt] = 1.0f / lsum;
    }

    // epilogue: O row q needs inv from column-lane q: broadcast via shfl
    #pragma unroll
    for (int mt = 0; mt < 2; ++mt) {
        #pragma unroll
        for (int r = 0; r < 4; ++r) {
            float ir = __shfl(inv[mt], quad * 4 + r, 64);
            int s = q0 + wave * 32 + mt * 16 + quad * 4 + r;
            #pragma unroll
            for (int dt = 0; dt < 4; ++dt) {
                int d = dt * 16 + lm;
                size_t off = (size_t)(b * SEQ + s) * D_MODEL + h * HD + d;
                float val = O[mt][dt][r] * ir;
                if (isbf) ((bf16*)out)[off] = __float2bfloat16(val);
                else      ((float*)out)[off] = val;
            }
        }
    }
}

extern "C" void kernel_launch(void* const* d_in, const int* in_sizes, int n_in,
                              void* d_out, int out_size, void* d_ws, size_t ws_size,
                              hipStream_t stream) {
    const void* x  = d_in[0];
    const void* Wq = d_in[1];
    const void* bq = d_in[2];
    const void* Wk = d_in[3];
    const void* bk = d_in[4];
    const void* Wv = d_in[5];
    const void* bv = d_in[6];

    char* ws = (char*)d_ws;
    int*  flag = (int*)ws;
    bf16* wbf  = (bf16*)(ws + 256);                              // 3 * 1048576 bf16
    bf16* bbf  = (bf16*)(ws + 256 + 3 * (size_t)WELEMS * 2);     // 3 * 1024 bf16
    bf16* qws  = (bf16*)(ws + 256 + 3 * (size_t)WELEMS * 2 + 8192);
    const size_t per = (size_t)BATCH * NHEADS * SEQ * HD;        // 8,388,608
    bf16* kws = qws + per;
    bf16* vws = kws + per;                                       // [B,H,64,S]

    // x (bf16) scratch lives in d_out: dead until attn's final write.
    bf16* xbf = (bf16*)d_out;

    detect_dtype<<<1, 64, 0, stream>>>((const unsigned short*)x, flag);

    const long ngroups = (long)XELEMS / 8 + 3L * (WELEMS / 8) + 3L * (D_MODEL / 8);
    convert_inputs<<<(int)((ngroups + 255) / 256), 256, 0, stream>>>(
        x, Wq, Wk, Wv, bq, bk, bv, xbf, wbf, bbf, flag);

    dim3 g1(64, 8, 3);        // M/128, N/128, {q,k,v}
    qkv_gemm<<<g1, 256, 0, stream>>>(xbf, wbf, bbf, qws, kws, vws);

    attn<<<1024, 256, 0, stream>>>(qws, kws, vws, d_out, flag);
}